// Round 5
// baseline (458.969 us; speedup 1.0000x reference)
//
#include <hip/hip_runtime.h>

#define NN   8192
#define FIN  128
#define HH   256
#define CAP  128   // max neighbors kept per row; E[deg]~32, max ~70, P(>128) ~ 0
#define BND  16    // nodes per fused block
#define NBLK (NN / BND)   // 512 blocks -> 2 per CU

typedef float f32x4 __attribute__((ext_vector_type(4)));
typedef float f32x2 __attribute__((ext_vector_type(2)));

__device__ __forceinline__ const f32x4* c4(const float* p) { return (const f32x4*)p; }
__device__ __forceinline__       f32x4* p4(float* p)       { return (f32x4*)p; }
__device__ __forceinline__ const f32x2* c2(const float* p) { return (const f32x2*)p; }
__device__ __forceinline__       f32x2* p2(float* p)       { return (f32x2*)p; }

// ---------------------------------------------------------------------------
// One block scans one row of A (nontemporal — read-once stream).
// cols/cnt: adjacency list; dinv = 1/sqrt(deg+1); expo = t*deg/(deg+1e-8).
// (unchanged — proven, HBM-bound at ~84% peak)
// ---------------------------------------------------------------------------
__global__ __launch_bounds__(256) void k_build(
    const float* __restrict__ A, const float* __restrict__ treat,
    int* __restrict__ cols, int* __restrict__ cnt,
    float* __restrict__ dinv, float* __restrict__ expo)
{
  const int row = blockIdx.x;
  const f32x4* Ar = c4(A + (size_t)row * NN);
  __shared__ int   s_cnt;
  __shared__ float s_rs[4];
  if (threadIdx.x == 0) s_cnt = 0;
  __syncthreads();

  float rs = 0.f;
  int* myCols = cols + (size_t)row * CAP;
  #pragma unroll
  for (int it = 0; it < NN / 4 / 256; ++it) {
    const int idx = it * 256 + threadIdx.x;
    const f32x4 a = __builtin_nontemporal_load(Ar + idx);
    const int base = idx * 4;
    #pragma unroll
    for (int u = 0; u < 4; ++u) {
      if (a[u] != 0.0f) {
        rs += a[u];
        int p = atomicAdd(&s_cnt, 1);
        if (p < CAP) myCols[p] = base + u;
      }
    }
  }
  #pragma unroll
  for (int off = 32; off > 0; off >>= 1) rs += __shfl_down(rs, off);
  const int wid = threadIdx.x >> 6;
  if ((threadIdx.x & 63) == 0) s_rs[wid] = rs;
  __syncthreads();
  if (threadIdx.x == 0) {
    const float R = s_rs[0] + s_rs[1] + s_rs[2] + s_rs[3];
    int n = s_cnt; if (n > CAP) n = CAP;
    cnt[row]  = n;
    dinv[row] = rsqrtf(R + 1.0f);
    expo[row] = treat[row] * R / (R + 1e-8f);
  }
}

// ---------------------------------------------------------------------------
// GEMM tile helper: acc[4][4] += h_tile[16 x K] @ W[K x 256]
// h in LDS (row stride hstride, 16B-aligned rows); W streamed via 16x256
// LDS panels (coalesced).  Thread (ty=wave 0..3, tx=lane 0..63) owns rows
// 4ty..4ty+3, cols 4tx..4tx+3.  A-reads are wave-uniform b128 broadcasts.
// ---------------------------------------------------------------------------
template<int K>
__device__ __forceinline__ void gemm_tile(
    const float* __restrict__ hbase, int hstride,
    const float* __restrict__ W, float (*w_lds)[HH + 4],
    int ty, int tx, int tid, float acc[4][4])
{
  #pragma unroll 1
  for (int k0 = 0; k0 < K; k0 += 16) {
    __syncthreads();                       // previous panel consumed / lds ready
    #pragma unroll
    for (int rr = 0; rr < 4; ++rr) {       // stage W[k0..k0+15][0..255]
      const int flat = rr * 1024 + tid * 4;
      const int row = flat >> 8, col = flat & 255;
      *p4(&w_lds[row][col]) = *c4(&W[(size_t)(k0 + row) * HH + col]);
    }
    __syncthreads();
    #pragma unroll
    for (int kk4 = 0; kk4 < 4; ++kk4) {
      f32x4 a4[4];
      #pragma unroll
      for (int i = 0; i < 4; ++i)
        a4[i] = *c4(&hbase[(size_t)(4 * ty + i) * hstride + k0 + 4 * kk4]);
      #pragma unroll
      for (int q = 0; q < 4; ++q) {
        const f32x4 b4 = *c4(&w_lds[4 * kk4 + q][4 * tx]);
        #pragma unroll
        for (int i = 0; i < 4; ++i)
          #pragma unroll
          for (int j = 0; j < 4; ++j)
            acc[i][j] += a4[i][q] * b4[j];
      }
    }
  }
}

// ---------------------------------------------------------------------------
// fused1: h1 = relu( (nA @ X) @ W1 + b1 )   for 16 nodes per block.
// Phase 1: gather X rows (128-wide, f32x2/lane) into LDS.  Phase 2: GEMM.
// ---------------------------------------------------------------------------
__global__ __launch_bounds__(256) void k_fused1(
    const float* __restrict__ X, const int* __restrict__ cols,
    const int* __restrict__ cnt, const float* __restrict__ dinv,
    const float* __restrict__ W1, const float* __restrict__ b1,
    float* __restrict__ h1)
{
  __shared__ float h_lds[BND][FIN + 4];     // gathered (nA@X) tile
  __shared__ float w_lds[16][HH + 4];       // W k-panel
  __shared__ int   s_cnt[BND];
  __shared__ int   s_colsG[BND][CAP];
  __shared__ float s_wG[BND][CAP];

  const int tid = threadIdx.x;
  const int ty = tid >> 6, tx = tid & 63;
  const int r0 = blockIdx.x * BND;

  if (tid < BND) s_cnt[tid] = cnt[r0 + tid];
  __syncthreads();
  for (int e = tid; e < BND * CAP; e += 256) {
    const int node = e >> 7, t = e & (CAP - 1);
    if (t < s_cnt[node]) {
      const int j = cols[(size_t)(r0 + node) * CAP + t];
      s_colsG[node][t] = j;
      s_wG[node][t]    = dinv[j];
    }
  }
  __syncthreads();

  #pragma unroll 1
  for (int s = 0; s < 4; ++s) {            // 4 nodes per wave
    const int lr = ty * 4 + s;
    const int i  = r0 + lr;
    const float di = dinv[i];
    const int n = s_cnt[lr];
    f32x2 acc = *c2(&X[(size_t)i * FIN + 2 * tx]);
    acc *= di;                              // self-loop
    #pragma unroll 4
    for (int t = 0; t < n; ++t) {
      const int   j = s_colsG[lr][t];
      const float w = s_wG[lr][t];
      acc += w * (*c2(&X[(size_t)j * FIN + 2 * tx]));
    }
    *p2(&h_lds[lr][2 * tx]) = di * acc;
  }

  float acc[4][4] = {};
  gemm_tile<FIN>(&h_lds[0][0], FIN + 4, W1, w_lds, ty, tx, tid, acc);

  const f32x4 bs = *c4(&b1[4 * tx]);
  #pragma unroll
  for (int i = 0; i < 4; ++i) {
    const int r = r0 + 4 * ty + i;
    f32x4 o;
    #pragma unroll
    for (int j = 0; j < 4; ++j) o[j] = fmaxf(acc[i][j] + bs[j], 0.f);
    *p4(&h1[(size_t)r * HH + 4 * tx]) = o;
  }
}

// ---------------------------------------------------------------------------
// mega: for 16 nodes per block:
//   g   = nA @ h1                       (gather, f32x4/lane, into LDS)
//   h2  = relu(g @ W2 + b2)             (GEMM1, into LDS)
//   emb = relu(h2 @ W_emb + expo*W_emb[256] + b_emb)   -> d_out
//   y0/y1 = emb @ W_t0/1 + b            (in-wave shfl reduce, no atomics)
// ---------------------------------------------------------------------------
__global__ __launch_bounds__(256) void k_mega(
    const float* __restrict__ H1, const int* __restrict__ cols,
    const int* __restrict__ cnt, const float* __restrict__ dinv,
    const float* __restrict__ expo,
    const float* __restrict__ W2, const float* __restrict__ b2,
    const float* __restrict__ W_emb, const float* __restrict__ b_emb,
    const float* __restrict__ W_t0, const float* __restrict__ b_t0,
    const float* __restrict__ W_t1, const float* __restrict__ b_t1,
    float* __restrict__ emb, float* __restrict__ y0, float* __restrict__ y1)
{
  __shared__ float h_lds[BND][HH + 4];      // gathered (nA@h1) tile
  __shared__ float g_lds[BND][HH + 4];      // h2 tile
  __shared__ float w_lds[16][HH + 4];       // W k-panel
  __shared__ int   s_cnt[BND];
  __shared__ int   s_colsG[BND][CAP];
  __shared__ float s_wG[BND][CAP];

  const int tid = threadIdx.x;
  const int ty = tid >> 6, tx = tid & 63;
  const int r0 = blockIdx.x * BND;

  if (tid < BND) s_cnt[tid] = cnt[r0 + tid];
  __syncthreads();
  for (int e = tid; e < BND * CAP; e += 256) {
    const int node = e >> 7, t = e & (CAP - 1);
    if (t < s_cnt[node]) {
      const int j = cols[(size_t)(r0 + node) * CAP + t];
      s_colsG[node][t] = j;
      s_wG[node][t]    = dinv[j];
    }
  }
  __syncthreads();

  #pragma unroll 1
  for (int s = 0; s < 4; ++s) {            // 4 nodes per wave
    const int lr = ty * 4 + s;
    const int i  = r0 + lr;
    const float di = dinv[i];
    const int n = s_cnt[lr];
    f32x4 acc = *c4(&H1[(size_t)i * HH + 4 * tx]);
    acc *= di;                              // self-loop
    #pragma unroll 4
    for (int t = 0; t < n; ++t) {
      const int   j = s_colsG[lr][t];
      const float w = s_wG[lr][t];
      acc += w * (*c4(&H1[(size_t)j * HH + 4 * tx]));
    }
    *p4(&h_lds[lr][4 * tx]) = di * acc;
  }

  // ---- GEMM1: h2 = relu(g @ W2 + b2) -> g_lds
  float acc[4][4] = {};
  gemm_tile<HH>(&h_lds[0][0], HH + 4, W2, w_lds, ty, tx, tid, acc);
  {
    const f32x4 bs = *c4(&b2[4 * tx]);
    #pragma unroll
    for (int i = 0; i < 4; ++i) {
      f32x4 o;
      #pragma unroll
      for (int j = 0; j < 4; ++j) o[j] = fmaxf(acc[i][j] + bs[j], 0.f);
      *p4(&g_lds[4 * ty + i][4 * tx]) = o;
      #pragma unroll
      for (int j = 0; j < 4; ++j) acc[i][j] = 0.f;   // reuse for GEMM2
    }
  }

  // ---- GEMM2: emb = relu(h2 @ W_emb + expo*W_emb[HH] + b_emb), + heads
  gemm_tile<HH>(&g_lds[0][0], HH + 4, W_emb, w_lds, ty, tx, tid, acc);

  const f32x4 eb  = *c4(&W_emb[(size_t)HH * HH + 4 * tx]);  // exposure row
  const f32x4 bse = *c4(&b_emb[4 * tx]);
  const f32x4 wt0 = *c4(&W_t0[4 * tx]);
  const f32x4 wt1 = *c4(&W_t1[4 * tx]);
  const float bt0 = b_t0[0], bt1 = b_t1[0];
  #pragma unroll
  for (int i = 0; i < 4; ++i) {
    const int r = r0 + 4 * ty + i;
    const float e = expo[r];
    f32x4 o;
    #pragma unroll
    for (int j = 0; j < 4; ++j)
      o[j] = fmaxf(acc[i][j] + e * eb[j] + bse[j], 0.f);
    *p4(&emb[(size_t)r * HH + 4 * tx]) = o;
    // heads: wave ty exclusively owns row r -> full in-wave reduction
    float s0 = o[0]*wt0[0] + o[1]*wt0[1] + o[2]*wt0[2] + o[3]*wt0[3];
    float s1 = o[0]*wt1[0] + o[1]*wt1[1] + o[2]*wt1[2] + o[3]*wt1[3];
    #pragma unroll
    for (int off = 32; off > 0; off >>= 1) {
      s0 += __shfl_down(s0, off);
      s1 += __shfl_down(s1, off);
    }
    if (tx == 0) { y0[r] = s0 + bt0; y1[r] = s1 + bt1; }
  }
}

// ---------------------------------------------------------------------------
extern "C" void kernel_launch(void* const* d_in, const int* in_sizes, int n_in,
                              void* d_out, int out_size, void* d_ws, size_t ws_size,
                              hipStream_t stream)
{
  const float* A      = (const float*)d_in[0];
  const float* feats  = (const float*)d_in[1];
  const float* treat  = (const float*)d_in[2];
  const float* W1     = (const float*)d_in[3];
  const float* b1     = (const float*)d_in[4];
  const float* W2     = (const float*)d_in[5];
  const float* b2     = (const float*)d_in[6];
  const float* W_emb  = (const float*)d_in[7];
  const float* b_emb  = (const float*)d_in[8];
  const float* W_t0   = (const float*)d_in[9];
  const float* b_t0   = (const float*)d_in[10];
  const float* W_t1   = (const float*)d_in[11];
  const float* b_t1   = (const float*)d_in[12];
  float* dout = (float*)d_out;

  // workspace layout (~12.3 MiB, 16B-aligned)
  int*   cols = (int*)d_ws;                 // NN*CAP ints (4 MiB)
  int*   cnt  = cols + (size_t)NN * CAP;    // NN
  float* dinv = (float*)(cnt + NN);         // NN
  float* expo = dinv + NN;                  // NN
  float* bufH = expo + NN;                  // NN*HH (8 MiB): h1

  float* y0  = dout;
  float* y1  = dout + NN;
  float* emb = dout + 2 * NN;

  // 1. A scan: adjacency + norm + exposure (HBM-bound floor)
  k_build<<<NN, 256, 0, stream>>>(A, treat, cols, cnt, dinv, expo);
  // 2. h1 = relu((nA@X)@W1 + b1)
  k_fused1<<<NBLK, 256, 0, stream>>>(feats, cols, cnt, dinv, W1, b1, bufH);
  // 3. gather + W2 + relu + W_emb + expo + relu + heads
  k_mega<<<NBLK, 256, 0, stream>>>(bufH, cols, cnt, dinv, expo,
                                   W2, b2, W_emb, b_emb, W_t0, b_t0, W_t1, b_t1,
                                   emb, y0, y1);
}

// Round 6
// 444.779 us; speedup vs baseline: 1.0319x; 1.0319x over previous
//
#include <hip/hip_runtime.h>

#define NN   8192
#define FIN  128
#define HH   256
#define CAP  128   // max neighbors kept per row; E[deg]~32, max ~70, P(>128) ~ 0

typedef float f32x4 __attribute__((ext_vector_type(4)));
typedef float f32x2 __attribute__((ext_vector_type(2)));

__device__ __forceinline__ const f32x4* c4(const float* p) { return (const f32x4*)p; }
__device__ __forceinline__       f32x4* p4(float* p)       { return (f32x4*)p; }
__device__ __forceinline__ const f32x2* c2(const float* p) { return (const f32x2*)p; }
__device__ __forceinline__       f32x2* p2(float* p)       { return (f32x2*)p; }

// ---------------------------------------------------------------------------
// One block scans one row of A (nontemporal — read-once stream).
// cols/cnt: adjacency list; dinv = 1/sqrt(deg+1); expo = t*deg/(deg+1e-8).
// (unchanged — HBM-bound floor ~42 µs)
// ---------------------------------------------------------------------------
__global__ __launch_bounds__(256) void k_build(
    const float* __restrict__ A, const float* __restrict__ treat,
    int* __restrict__ cols, int* __restrict__ cnt,
    float* __restrict__ dinv, float* __restrict__ expo)
{
  const int row = blockIdx.x;
  const f32x4* Ar = c4(A + (size_t)row * NN);
  __shared__ int   s_cnt;
  __shared__ float s_rs[4];
  if (threadIdx.x == 0) s_cnt = 0;
  __syncthreads();

  float rs = 0.f;
  int* myCols = cols + (size_t)row * CAP;
  #pragma unroll
  for (int it = 0; it < NN / 4 / 256; ++it) {
    const int idx = it * 256 + threadIdx.x;
    const f32x4 a = __builtin_nontemporal_load(Ar + idx);
    const int base = idx * 4;
    #pragma unroll
    for (int u = 0; u < 4; ++u) {
      if (a[u] != 0.0f) {
        rs += a[u];
        int p = atomicAdd(&s_cnt, 1);
        if (p < CAP) myCols[p] = base + u;
      }
    }
  }
  #pragma unroll
  for (int off = 32; off > 0; off >>= 1) rs += __shfl_down(rs, off);
  const int wid = threadIdx.x >> 6;
  if ((threadIdx.x & 63) == 0) s_rs[wid] = rs;
  __syncthreads();
  if (threadIdx.x == 0) {
    const float R = s_rs[0] + s_rs[1] + s_rs[2] + s_rs[3];
    int n = s_cnt; if (n > CAP) n = CAP;
    cnt[row]  = n;
    dinv[row] = rsqrtf(R + 1.0f);
    expo[row] = treat[row] * R / (R + 1e-8f);
  }
}

// ---------------------------------------------------------------------------
// L2-tiled sparse aggregation.  gridDim.y = W/64 column tiles; each tile's
// gathered slice (8192 x 64 x 4B = 2 MB) fits a per-XCD L2, so the ~32x
// reuse is served at L2 BW instead of L3/HBM.  Wave per node, f32x1/lane
// (256 B/wave, coalesced).  y is slowest-varying -> tiles time-phased.
//   out[i,c] = [relu](dinv[i]*(sum_j dinv[j]*M[j,c] + dinv[i]*M[i,c]) [+ b[c]])
// INIT: y==0 early blocks also write head biases into y0/y1 (pre-atomics).
// ---------------------------------------------------------------------------
template<int W, bool RELU, bool INIT>
__global__ __launch_bounds__(256) void k_agg_t(
    const float* __restrict__ M,
    const int* __restrict__ cols, const int* __restrict__ cnt,
    const float* __restrict__ dinv, const float* __restrict__ bias,
    float* __restrict__ out,
    float* __restrict__ dout, const float* __restrict__ bt0, const float* __restrict__ bt1)
{
  const int wid  = threadIdx.x >> 6;
  const int lane = threadIdx.x & 63;
  const int i    = blockIdx.x * 4 + wid;
  const int c    = blockIdx.y * 64 + lane;
  __shared__ int   s_cols[4][CAP];
  __shared__ float s_w[4][CAP];

  if constexpr (INIT) {
    if (blockIdx.y == 0 && blockIdx.x < 64) {
      const int idx = blockIdx.x * 256 + threadIdx.x;   // 16384 = y0,y1
      dout[idx] = (idx < NN) ? bt0[0] : bt1[0];
    }
  }

  const int n = cnt[i];
  if (lane < n) {
    const int j = cols[(size_t)i * CAP + lane];
    s_cols[wid][lane] = j;  s_w[wid][lane] = dinv[j];
  }
  if (lane + 64 < n) {
    const int j = cols[(size_t)i * CAP + lane + 64];
    s_cols[wid][lane + 64] = j;  s_w[wid][lane + 64] = dinv[j];
  }
  __syncthreads();

  const float di = dinv[i];
  float acc = di * M[(size_t)i * W + c];   // self-loop term
  #pragma unroll 4
  for (int t = 0; t < n; ++t)
    acc += s_w[wid][t] * M[(size_t)s_cols[wid][t] * W + c];
  float v = di * acc;
  if constexpr (RELU) v = fmaxf(v + bias[c], 0.f);
  out[(size_t)i * W + c] = v;
}

// ---------------------------------------------------------------------------
// GEMM body: out[8192 x HH] = M[8192 x K] @ W[K x HH]
// 64x64 tile, 256 threads, 4x4 micro-tile, KT=16 LDS panels with register
// prefetch.  RELU: +bias, relu.  EXPO: + expo[r]*W[K][c] (implies RELU).
// HEADS: fused y0/y1 partial dots via shfl + atomics.  (unchanged, proven)
// ---------------------------------------------------------------------------
template<int K, bool RELU, bool EXPO, bool HEADS>
__device__ __forceinline__ void gemm_body(
    int bidx,
    const float* __restrict__ M, const float* __restrict__ W,
    const float* __restrict__ bias, const float* __restrict__ expo,
    const float* __restrict__ Wt0, const float* __restrict__ Wt1,
    float* __restrict__ out, float* __restrict__ y0, float* __restrict__ y1,
    float (*As)[64], float (*Bs)[64])
{
  const int tid = threadIdx.x;
  const int tx = tid & 15, ty = tid >> 4;
  const int bx = bidx & 127, by = bidx >> 7;
  const int r0 = bx * 64, c0 = by * 64;
  const int la_r = tid & 63;          // A row within tile
  const int la_k = (tid >> 6) << 2;   // A k offset: 0,4,8,12
  const int lb_k = tid >> 4;          // B k row 0..15
  const int lb_c = (tid & 15) << 2;   // B col offset

  const float* Abase = M + (size_t)(r0 + la_r) * K + la_k;
  const float* Bbase = W + (size_t)lb_k * HH + c0 + lb_c;

  f32x4 aR = *c4(Abase);
  f32x4 bR = *c4(Bbase);
  float acc[4][4] = {};

  #pragma unroll 1
  for (int k0 = 0; k0 < K; k0 += 16) {
    As[la_k + 0][la_r] = aR[0];
    As[la_k + 1][la_r] = aR[1];
    As[la_k + 2][la_r] = aR[2];
    As[la_k + 3][la_r] = aR[3];
    *p4(&Bs[lb_k][lb_c]) = bR;
    __syncthreads();
    if (k0 + 16 < K) {                       // prefetch next panel into regs
      aR = *c4(Abase + k0 + 16);
      bR = *c4(Bbase + (size_t)(k0 + 16) * HH);
    }
    #pragma unroll
    for (int kk = 0; kk < 16; ++kk) {
      const f32x4 av = *c4(&As[kk][ty * 4]);
      const f32x4 bv = *c4(&Bs[kk][tx * 4]);
      #pragma unroll
      for (int i = 0; i < 4; ++i)
        #pragma unroll
        for (int j = 0; j < 4; ++j)
          acc[i][j] += av[i] * bv[j];
    }
    __syncthreads();
  }

  f32x4 eb = {0.f, 0.f, 0.f, 0.f}, bs = {0.f, 0.f, 0.f, 0.f};
  if constexpr (RELU) bs = *c4(&bias[c0 + tx * 4]);
  if constexpr (EXPO) eb = *c4(&W[(size_t)K * HH + c0 + tx * 4]);  // exposure row
  f32x4 wt0 = {0.f, 0.f, 0.f, 0.f}, wt1 = {0.f, 0.f, 0.f, 0.f};
  if constexpr (HEADS) {
    wt0 = *c4(&Wt0[c0 + tx * 4]);
    wt1 = *c4(&Wt1[c0 + tx * 4]);
  }
  #pragma unroll
  for (int i = 0; i < 4; ++i) {
    const int r = r0 + ty * 4 + i;
    f32x4 o;
    if constexpr (RELU) {
      float e = 0.f;
      if constexpr (EXPO) e = expo[r];
      #pragma unroll
      for (int j = 0; j < 4; ++j) {
        float v = acc[i][j] + bs[j];
        if constexpr (EXPO) v += e * eb[j];
        o[j] = fmaxf(v, 0.f);
      }
    } else {
      #pragma unroll
      for (int j = 0; j < 4; ++j) o[j] = acc[i][j];
    }
    *p4(&out[(size_t)r * HH + c0 + tx * 4]) = o;
    if constexpr (HEADS) {
      float s0 = o[0] * wt0[0] + o[1] * wt0[1] + o[2] * wt0[2] + o[3] * wt0[3];
      float s1 = o[0] * wt1[0] + o[1] * wt1[1] + o[2] * wt1[2] + o[3] * wt1[3];
      #pragma unroll
      for (int off = 8; off > 0; off >>= 1) {
        s0 += __shfl_down(s0, off);
        s1 += __shfl_down(s1, off);
      }
      if ((tid & 15) == 0) {
        atomicAdd(&y0[r], s0);
        atomicAdd(&y1[r], s1);
      }
    }
  }
}

template<int K, bool RELU, bool EXPO, bool HEADS>
__global__ __launch_bounds__(256) void k_gemm(
    const float* __restrict__ M, const float* __restrict__ W,
    const float* __restrict__ bias, const float* __restrict__ expo,
    const float* __restrict__ Wt0, const float* __restrict__ Wt1,
    float* __restrict__ out, float* __restrict__ y0, float* __restrict__ y1)
{
  __shared__ float As[16][64];
  __shared__ float Bs[16][64];
  gemm_body<K, RELU, EXPO, HEADS>(blockIdx.x, M, W, bias, expo, Wt0, Wt1,
                                  out, y0, y1, As, Bs);
}

// ---------------------------------------------------------------------------
extern "C" void kernel_launch(void* const* d_in, const int* in_sizes, int n_in,
                              void* d_out, int out_size, void* d_ws, size_t ws_size,
                              hipStream_t stream)
{
  const float* A      = (const float*)d_in[0];
  const float* feats  = (const float*)d_in[1];
  const float* treat  = (const float*)d_in[2];
  const float* W1     = (const float*)d_in[3];
  const float* b1     = (const float*)d_in[4];
  const float* W2     = (const float*)d_in[5];
  const float* b2     = (const float*)d_in[6];
  const float* W_emb  = (const float*)d_in[7];
  const float* b_emb  = (const float*)d_in[8];
  const float* W_t0   = (const float*)d_in[9];
  const float* b_t0   = (const float*)d_in[10];
  const float* W_t1   = (const float*)d_in[11];
  const float* b_t1   = (const float*)d_in[12];
  float* dout = (float*)d_out;

  // workspace layout (~24 MiB, all 16B-aligned)
  int*   cols = (int*)d_ws;                 // NN*CAP ints (4 MiB)
  int*   cnt  = cols + (size_t)NN * CAP;    // NN
  float* dinv = (float*)(cnt + NN);         // NN
  float* expo = dinv + NN;                  // NN
  float* bufX = expo + NN;                  // NN*FIN (4 MiB)
  float* bufA = bufX + (size_t)NN * FIN;    // NN*HH  (8 MiB)
  float* bufB = bufA + (size_t)NN * HH;     // NN*HH  (8 MiB)

  float* y0  = dout;
  float* y1  = dout + NN;
  float* emb = dout + 2 * NN;

  // 1. A scan: adjacency + norm + exposure
  k_build<<<NN, 256, 0, stream>>>(A, treat, cols, cnt, dinv, expo);
  // 2. aggX = nA @ X   (L2-tiled: 2 x 64-col passes, 2 MB resident slice)
  k_agg_t<FIN, false, false><<<dim3(NN / 4, FIN / 64), 256, 0, stream>>>(
      feats, cols, cnt, dinv, nullptr, bufX, nullptr, nullptr, nullptr);
  // 3. h1 = relu(aggX @ W1 + b1)
  k_gemm<FIN, true, false, false><<<512, 256, 0, stream>>>(
      bufX, W1, b1, nullptr, nullptr, nullptr, bufB, nullptr, nullptr);
  // 4. h1W2 = h1 @ W2
  k_gemm<HH, false, false, false><<<512, 256, 0, stream>>>(
      bufB, W2, nullptr, nullptr, nullptr, nullptr, bufA, nullptr, nullptr);
  // 5. h2 = relu(nA @ h1W2 + b2)  (L2-tiled: 4 x 64-col passes; + y0/y1 init)
  k_agg_t<HH, true, true><<<dim3(NN / 4, HH / 64), 256, 0, stream>>>(
      bufA, cols, cnt, dinv, b2, bufB, dout, b_t0, b_t1);
  // 6. emb = relu([h2, expo] @ W_emb + b_emb) -> d_out, fused y0/y1 heads
  k_gemm<HH, true, true, true><<<512, 256, 0, stream>>>(
      bufB, W_emb, b_emb, expo, W_t0, W_t1, emb, y0, y1);
}

// Round 7
// 430.851 us; speedup vs baseline: 1.0653x; 1.0323x over previous
//
#include <hip/hip_runtime.h>

#define NN   8192
#define FIN  128
#define HH   256
#define CAP  128   // max neighbors kept per row; E[deg]~32, max ~70, P(>128) ~ 0

typedef float    f32x4 __attribute__((ext_vector_type(4)));
typedef float    f32x2 __attribute__((ext_vector_type(2)));
typedef _Float16 f16x4 __attribute__((ext_vector_type(4)));
typedef _Float16 f16x2 __attribute__((ext_vector_type(2)));

__device__ __forceinline__ const f32x4* c4(const float* p) { return (const f32x4*)p; }
__device__ __forceinline__       f32x4* p4(float* p)       { return (f32x4*)p; }
__device__ __forceinline__ const f32x2* c2(const float* p) { return (const f32x2*)p; }
__device__ __forceinline__       f32x2* p2(float* p)       { return (f32x2*)p; }

// ---------------------------------------------------------------------------
// Blocks 0..NN-1: scan one row of A (nontemporal stream) -> adjacency list,
// dinv = 1/sqrt(deg+1), expo = t*deg/(deg+1e-8).
// Blocks NN..NN+127: convert X to fp16 (hidden under the BW-bound scan).
// ---------------------------------------------------------------------------
__global__ __launch_bounds__(256) void k_build(
    const float* __restrict__ A, const float* __restrict__ treat,
    const float* __restrict__ X,
    int* __restrict__ cols, int* __restrict__ cnt,
    float* __restrict__ dinv, float* __restrict__ expo,
    _Float16* __restrict__ Xh)
{
  const int row = blockIdx.x;
  if (row >= NN) {                    // X -> fp16 conversion tail
    const int t0 = (row - NN) * 256 + threadIdx.x;
    for (int i = t0; i < NN * FIN / 4; i += 128 * 256) {
      const f32x4 v = *c4(&X[(size_t)i * 4]);
      f16x4 h = {(_Float16)v[0], (_Float16)v[1], (_Float16)v[2], (_Float16)v[3]};
      *(f16x4*)&Xh[(size_t)i * 4] = h;
    }
    return;
  }

  const f32x4* Ar = c4(A + (size_t)row * NN);
  __shared__ int   s_cnt;
  __shared__ float s_rs[4];
  if (threadIdx.x == 0) s_cnt = 0;
  __syncthreads();

  float rs = 0.f;
  int* myCols = cols + (size_t)row * CAP;
  #pragma unroll
  for (int it = 0; it < NN / 4 / 256; ++it) {
    const int idx = it * 256 + threadIdx.x;
    const f32x4 a = __builtin_nontemporal_load(Ar + idx);
    const int base = idx * 4;
    #pragma unroll
    for (int u = 0; u < 4; ++u) {
      if (a[u] != 0.0f) {
        rs += a[u];
        int p = atomicAdd(&s_cnt, 1);
        if (p < CAP) myCols[p] = base + u;
      }
    }
  }
  #pragma unroll
  for (int off = 32; off > 0; off >>= 1) rs += __shfl_down(rs, off);
  const int wid = threadIdx.x >> 6;
  if ((threadIdx.x & 63) == 0) s_rs[wid] = rs;
  __syncthreads();
  if (threadIdx.x == 0) {
    const float R = s_rs[0] + s_rs[1] + s_rs[2] + s_rs[3];
    int n = s_cnt; if (n > CAP) n = CAP;
    cnt[row]  = n;
    dinv[row] = rsqrtf(R + 1.0f);
    expo[row] = treat[row] * R / (R + 1e-8f);
  }
}

// ---------------------------------------------------------------------------
// agg0: out[i,:] = dinv[i]*(sum_j dinv[j]*Xh[j,:] + dinv[i]*Xh[i,:])
// fp16 gather (half bytes), fp32 accumulate.  Wave per node, f16x2/lane.
// ---------------------------------------------------------------------------
__global__ __launch_bounds__(256) void k_agg0h(
    const _Float16* __restrict__ Xh,
    const int* __restrict__ cols, const int* __restrict__ cnt,
    const float* __restrict__ dinv, float* __restrict__ out)
{
  const int wid  = threadIdx.x >> 6;
  const int lane = threadIdx.x & 63;
  const int i    = blockIdx.x * 4 + wid;
  __shared__ int   s_cols[4][CAP];
  __shared__ float s_w[4][CAP];

  const int n = cnt[i];
  if (lane < n) {
    const int j = cols[(size_t)i * CAP + lane];
    s_cols[wid][lane] = j;  s_w[wid][lane] = dinv[j];
  }
  if (lane + 64 < n) {
    const int j = cols[(size_t)i * CAP + lane + 64];
    s_cols[wid][lane + 64] = j;  s_w[wid][lane + 64] = dinv[j];
  }
  __syncthreads();

  const float di = dinv[i];
  const f16x2 sv = *(const f16x2*)&Xh[(size_t)i * FIN + 2 * lane];
  f32x2 acc = {di * (float)sv[0], di * (float)sv[1]};
  #pragma unroll 4
  for (int t = 0; t < n; ++t) {
    const int   j = s_cols[wid][t];
    const float w = s_w[wid][t];
    const f16x2 v = *(const f16x2*)&Xh[(size_t)j * FIN + 2 * lane];
    acc[0] += w * (float)v[0];
    acc[1] += w * (float)v[1];
  }
  *p2(&out[(size_t)i * FIN + 2 * lane]) = di * acc;
}

// ---------------------------------------------------------------------------
// agg on 256-wide fp16 M: out[i,:] = relu(dinv[i]*(sum dinv[j]*M[j,:]
//   + dinv[i]*M[i,:]) + b).  fp16 gather, fp32 accumulate, fp32 out.
// INIT: first blocks also write head biases into y0/y1.
// ---------------------------------------------------------------------------
template<bool INIT>
__global__ __launch_bounds__(256) void k_aggh(
    const _Float16* __restrict__ M,
    const int* __restrict__ cols, const int* __restrict__ cnt,
    const float* __restrict__ dinv, const float* __restrict__ bias,
    float* __restrict__ out,
    float* __restrict__ dout, const float* __restrict__ bt0, const float* __restrict__ bt1)
{
  const int wid  = threadIdx.x >> 6;
  const int lane = threadIdx.x & 63;
  const int i    = blockIdx.x * 4 + wid;
  __shared__ int   s_cols[4][CAP];
  __shared__ float s_w[4][CAP];

  if constexpr (INIT) {
    if (blockIdx.x < 64) {
      const int idx = blockIdx.x * 256 + threadIdx.x;   // 16384 = y0,y1
      dout[idx] = (idx < NN) ? bt0[0] : bt1[0];
    }
  }

  const int n = cnt[i];
  if (lane < n) {
    const int j = cols[(size_t)i * CAP + lane];
    s_cols[wid][lane] = j;  s_w[wid][lane] = dinv[j];
  }
  if (lane + 64 < n) {
    const int j = cols[(size_t)i * CAP + lane + 64];
    s_cols[wid][lane + 64] = j;  s_w[wid][lane + 64] = dinv[j];
  }
  __syncthreads();

  const float di = dinv[i];
  const f32x4 bias4 = *c4(&bias[lane * 4]);
  const f16x4 sv = *(const f16x4*)&M[(size_t)i * HH + 4 * lane];
  f32x4 acc = {di * (float)sv[0], di * (float)sv[1],
               di * (float)sv[2], di * (float)sv[3]};
  #pragma unroll 4
  for (int t = 0; t < n; ++t) {
    const int   j = s_cols[wid][t];
    const float w = s_w[wid][t];
    const f16x4 v = *(const f16x4*)&M[(size_t)j * HH + 4 * lane];
    acc[0] += w * (float)v[0];
    acc[1] += w * (float)v[1];
    acc[2] += w * (float)v[2];
    acc[3] += w * (float)v[3];
  }
  f32x4 o = di * acc + bias4;
  #pragma unroll
  for (int q = 0; q < 4; ++q) o[q] = fmaxf(o[q], 0.f);
  *p4(&out[(size_t)i * HH + 4 * lane]) = o;
}

// ---------------------------------------------------------------------------
// GEMM body: out[8192 x HH] = M[8192 x K] @ W[K x HH]
// 64x64 tile, 256 threads, 4x4 micro-tile, KT=16 LDS panels with register
// prefetch.  RELU: +bias, relu.  EXPO: + expo[r]*W[K][c] (implies RELU).
// HEADS: fused y0/y1 dots.  F16OUT: write fp16 (for the pre-gather buffer).
// ---------------------------------------------------------------------------
template<int K, bool RELU, bool EXPO, bool HEADS, bool F16OUT>
__device__ __forceinline__ void gemm_body(
    int bidx,
    const float* __restrict__ M, const float* __restrict__ W,
    const float* __restrict__ bias, const float* __restrict__ expo,
    const float* __restrict__ Wt0, const float* __restrict__ Wt1,
    float* __restrict__ out, _Float16* __restrict__ out16,
    float* __restrict__ y0, float* __restrict__ y1,
    float (*As)[64], float (*Bs)[64])
{
  const int tid = threadIdx.x;
  const int tx = tid & 15, ty = tid >> 4;
  const int bx = bidx & 127, by = bidx >> 7;
  const int r0 = bx * 64, c0 = by * 64;
  const int la_r = tid & 63;          // A row within tile
  const int la_k = (tid >> 6) << 2;   // A k offset: 0,4,8,12
  const int lb_k = tid >> 4;          // B k row 0..15
  const int lb_c = (tid & 15) << 2;   // B col offset

  const float* Abase = M + (size_t)(r0 + la_r) * K + la_k;
  const float* Bbase = W + (size_t)lb_k * HH + c0 + lb_c;

  f32x4 aR = *c4(Abase);
  f32x4 bR = *c4(Bbase);
  float acc[4][4] = {};

  #pragma unroll 1
  for (int k0 = 0; k0 < K; k0 += 16) {
    As[la_k + 0][la_r] = aR[0];
    As[la_k + 1][la_r] = aR[1];
    As[la_k + 2][la_r] = aR[2];
    As[la_k + 3][la_r] = aR[3];
    *p4(&Bs[lb_k][lb_c]) = bR;
    __syncthreads();
    if (k0 + 16 < K) {                       // prefetch next panel into regs
      aR = *c4(Abase + k0 + 16);
      bR = *c4(Bbase + (size_t)(k0 + 16) * HH);
    }
    #pragma unroll
    for (int kk = 0; kk < 16; ++kk) {
      const f32x4 av = *c4(&As[kk][ty * 4]);
      const f32x4 bv = *c4(&Bs[kk][tx * 4]);
      #pragma unroll
      for (int i = 0; i < 4; ++i)
        #pragma unroll
        for (int j = 0; j < 4; ++j)
          acc[i][j] += av[i] * bv[j];
    }
    __syncthreads();
  }

  f32x4 eb = {0.f, 0.f, 0.f, 0.f}, bs = {0.f, 0.f, 0.f, 0.f};
  if constexpr (RELU) bs = *c4(&bias[c0 + tx * 4]);
  if constexpr (EXPO) eb = *c4(&W[(size_t)K * HH + c0 + tx * 4]);  // exposure row
  f32x4 wt0 = {0.f, 0.f, 0.f, 0.f}, wt1 = {0.f, 0.f, 0.f, 0.f};
  if constexpr (HEADS) {
    wt0 = *c4(&Wt0[c0 + tx * 4]);
    wt1 = *c4(&Wt1[c0 + tx * 4]);
  }
  #pragma unroll
  for (int i = 0; i < 4; ++i) {
    const int r = r0 + ty * 4 + i;
    f32x4 o;
    if constexpr (RELU) {
      float e = 0.f;
      if constexpr (EXPO) e = expo[r];
      #pragma unroll
      for (int j = 0; j < 4; ++j) {
        float v = acc[i][j] + bs[j];
        if constexpr (EXPO) v += e * eb[j];
        o[j] = fmaxf(v, 0.f);
      }
    } else {
      #pragma unroll
      for (int j = 0; j < 4; ++j) o[j] = acc[i][j];
    }
    if constexpr (F16OUT) {
      f16x4 oh = {(_Float16)o[0], (_Float16)o[1], (_Float16)o[2], (_Float16)o[3]};
      *(f16x4*)&out16[(size_t)r * HH + c0 + tx * 4] = oh;
    } else {
      *p4(&out[(size_t)r * HH + c0 + tx * 4]) = o;
    }
    if constexpr (HEADS) {
      float s0 = o[0] * wt0[0] + o[1] * wt0[1] + o[2] * wt0[2] + o[3] * wt0[3];
      float s1 = o[0] * wt1[0] + o[1] * wt1[1] + o[2] * wt1[2] + o[3] * wt1[3];
      #pragma unroll
      for (int off = 8; off > 0; off >>= 1) {
        s0 += __shfl_down(s0, off);
        s1 += __shfl_down(s1, off);
      }
      if ((tid & 15) == 0) {
        atomicAdd(&y0[r], s0);
        atomicAdd(&y1[r], s1);
      }
    }
  }
}

template<int K, bool RELU, bool EXPO, bool HEADS, bool F16OUT>
__global__ __launch_bounds__(256) void k_gemm(
    const float* __restrict__ M, const float* __restrict__ W,
    const float* __restrict__ bias, const float* __restrict__ expo,
    const float* __restrict__ Wt0, const float* __restrict__ Wt1,
    float* __restrict__ out, _Float16* __restrict__ out16,
    float* __restrict__ y0, float* __restrict__ y1)
{
  __shared__ float As[16][64];
  __shared__ float Bs[16][64];
  gemm_body<K, RELU, EXPO, HEADS, F16OUT>(blockIdx.x, M, W, bias, expo, Wt0, Wt1,
                                          out, out16, y0, y1, As, Bs);
}

// ---------------------------------------------------------------------------
extern "C" void kernel_launch(void* const* d_in, const int* in_sizes, int n_in,
                              void* d_out, int out_size, void* d_ws, size_t ws_size,
                              hipStream_t stream)
{
  const float* A      = (const float*)d_in[0];
  const float* feats  = (const float*)d_in[1];
  const float* treat  = (const float*)d_in[2];
  const float* W1     = (const float*)d_in[3];
  const float* b1     = (const float*)d_in[4];
  const float* W2     = (const float*)d_in[5];
  const float* b2     = (const float*)d_in[6];
  const float* W_emb  = (const float*)d_in[7];
  const float* b_emb  = (const float*)d_in[8];
  const float* W_t0   = (const float*)d_in[9];
  const float* b_t0   = (const float*)d_in[10];
  const float* W_t1   = (const float*)d_in[11];
  const float* b_t1   = (const float*)d_in[12];
  float* dout = (float*)d_out;

  // workspace layout (~22.3 MiB, all 16B-aligned)
  int*      cols   = (int*)d_ws;                        // NN*CAP ints (4 MiB)
  int*      cnt    = cols + (size_t)NN * CAP;           // NN
  float*    dinv   = (float*)(cnt + NN);                // NN
  float*    expo   = dinv + NN;                         // NN
  float*    bufX   = expo + NN;                         // NN*FIN f32 (4 MiB)
  float*    bufB   = bufX + (size_t)NN * FIN;           // NN*HH  f32 (8 MiB)
  _Float16* Xh     = (_Float16*)(bufB + (size_t)NN * HH);   // NN*FIN f16 (2 MiB)
  _Float16* bufA16 = Xh + (size_t)NN * FIN;             // NN*HH f16 (4 MiB)

  float* y0  = dout;
  float* y1  = dout + NN;
  float* emb = dout + 2 * NN;

  // 1. A scan (adjacency+norm+exposure) + X->fp16 tail blocks
  k_build<<<NN + 128, 256, 0, stream>>>(A, treat, feats, cols, cnt, dinv, expo, Xh);
  // 2. aggX = nA @ X   (fp16 gather: 67 MB instead of 134)
  k_agg0h<<<NN / 4, 256, 0, stream>>>(Xh, cols, cnt, dinv, bufX);
  // 3. h1 = relu(aggX @ W1 + b1)            (fp32)
  k_gemm<FIN, true, false, false, false><<<512, 256, 0, stream>>>(
      bufX, W1, b1, nullptr, nullptr, nullptr, bufB, nullptr, nullptr, nullptr);
  // 4. h1W2 = h1 @ W2 -> fp16 buffer        (halves the next gather)
  k_gemm<HH, false, false, false, true><<<512, 256, 0, stream>>>(
      bufB, W2, nullptr, nullptr, nullptr, nullptr, nullptr, bufA16, nullptr, nullptr);
  // 5. h2 = relu(nA @ h1W2 + b2)  (fp16 gather: 134 MB instead of 268; + y-init)
  k_aggh<true><<<NN / 4, 256, 0, stream>>>(bufA16, cols, cnt, dinv, b2, bufB,
                                           dout, b_t0, b_t1);
  // 6. emb = relu([h2, expo] @ W_emb + b_emb) -> d_out, fused y0/y1 heads
  k_gemm<HH, true, true, true, false><<<512, 256, 0, stream>>>(
      bufB, W_emb, b_emb, expo, W_t0, W_t1, emb, nullptr, y0, y1);
}